// Round 13
// baseline (449.075 us; speedup 1.0000x reference)
//
#include <hip/hip_runtime.h>

#define DIMC 3072
#define NH 24
#define HD 128
#define QKV_N 9216
#define S_TXT 256
#define S_IMG 2048
#define S_TOT 2304

typedef _Float16 f16x8 __attribute__((ext_vector_type(8)));
typedef _Float16 f16x4 __attribute__((ext_vector_type(4)));
typedef _Float16 f16x2 __attribute__((ext_vector_type(2)));
typedef float f32x4 __attribute__((ext_vector_type(4)));

#define MFMA(A, B, C) __builtin_amdgcn_mfma_f32_16x16x32_f16(A, B, C, 0, 0, 0)

// scale(1/sqrt(128)) * log2(e): scores computed directly in log2 domain
#define QSCALE (0.08838834764831845f * 1.4426950408889634f)

// direct global->LDS async copy, 16B per lane; lds base must be wave-uniform
__device__ __forceinline__ void gl2lds16(const _Float16* g, _Float16* l) {
    __builtin_amdgcn_global_load_lds(
        (const __attribute__((address_space(1))) unsigned int*)g,
        (__attribute__((address_space(3))) unsigned int*)l,
        16, 0, 0);
}

// ---------------------------------------------------------------------------
// prep: one launch for concat->fp16 + both W transposes.
// ---------------------------------------------------------------------------
__global__ __launch_bounds__(256) void prep(
    const float* __restrict__ enc, const float* __restrict__ hid,
    const float* __restrict__ Wqkv, const float* __restrict__ Wout,
    _Float16* __restrict__ xh, _Float16* __restrict__ Wth,
    _Float16* __restrict__ W2h)
{
    __shared__ float T[64][68];
    const int bid = blockIdx.x;
    const int t = threadIdx.x;

    if (bid < S_TOT) {
        const int s = bid;
        const float* src = (s < S_TXT) ? enc + (size_t)s * DIMC
                                       : hid + (size_t)(s - S_TXT) * DIMC;
#pragma unroll
        for (int it = 0; it < 3; ++it) {
            const int i = (it * 256 + t) * 4;
            float4 v = *(const float4*)(src + i);
            f16x4 hv;
            hv.x = (_Float16)v.x; hv.y = (_Float16)v.y;
            hv.z = (_Float16)v.z; hv.w = (_Float16)v.w;
            *(f16x4*)(xh + (size_t)s * DIMC + i) = hv;
        }
        return;
    }

    const float* W;
    _Float16* Th;
    int n0, k0, ldw;
    if (bid < S_TOT + 144 * 48) {
        const int b2 = bid - S_TOT;
        W = Wqkv; Th = Wth; ldw = QKV_N;
        n0 = (b2 % 144) * 64; k0 = (b2 / 144) * 64;
    } else {
        const int b2 = bid - S_TOT - 144 * 48;
        W = Wout; Th = W2h; ldw = DIMC;
        n0 = (b2 % 48) * 64; k0 = (b2 / 48) * 64;
    }
    {
        const int r = t >> 2, c4 = (t & 3) * 16;
#pragma unroll
        for (int j = 0; j < 4; ++j) {
            float4 v = *(const float4*)(W + (size_t)(k0 + r) * ldw + n0 + c4 + j * 4);
            *(float4*)&T[r][c4 + j * 4] = v;
        }
    }
    __syncthreads();
    const int nr = t >> 2, kp = (t & 3) * 16;
    f16x8 hv0, hv1;
#pragma unroll
    for (int j = 0; j < 8; ++j) hv0[j] = (_Float16)T[kp + j][nr];
#pragma unroll
    for (int j = 0; j < 8; ++j) hv1[j] = (_Float16)T[kp + 8 + j][nr];
    _Float16* dh = Th + (size_t)(n0 + nr) * DIMC + k0 + kp;
    *(f16x8*)(dh) = hv0; *(f16x8*)(dh + 8) = hv1;
}

// ===========================================================================
// 2-phase single-buffer GEMM core (R10-verified: 183 us, MfmaUtil 31%,
// 0 conflicts). 128x128 tile, BK=32, 4 waves 2x2, gl2lds w16.
// T1 XCD-chunked swizzle + T2 both-sides slot-XOR.
// ===========================================================================
#define GEMM_PRE()                                                            \
    const int cpx = (int)gridDim.x >> 3;                                      \
    const int wgid = (blockIdx.x & 7) * cpx + (blockIdx.x >> 3);              \
    const int bm = (wgid % 18) * 128;                                         \
    const int bn = (wgid / 18) * 128;                                         \
    const int tid = threadIdx.x;                                              \
    const int l = tid & 63, w = tid >> 6;                                     \
    const int wr = w >> 1, wc = w & 1;                                        \
    const int lr = l & 15, g = l >> 4;                                        \
    const int srow0 = w * 32 + (l >> 2);                                      \
    const int srow1 = srow0 + 16;                                             \
    const int skp0 = (((l & 3) ^ ((srow0 >> 1) & 3)) * 8);                    \
    const int skp1 = (((l & 3) ^ ((srow1 >> 1) & 3)) * 8);                    \
    const _Float16* gA0 = Ah + (size_t)(bm + srow0) * DIMC + skp0;            \
    const _Float16* gA1 = Ah + (size_t)(bm + srow1) * DIMC + skp1;            \
    const _Float16* gB0 = Bh + (size_t)(bn + srow0) * DIMC + skp0;            \
    const _Float16* gB1 = Bh + (size_t)(bn + srow1) * DIMC + skp1;            \
    _Float16* lA0 = &Ash[(w * 32) * 32];                                      \
    _Float16* lA1 = &Ash[(w * 32 + 16) * 32];                                 \
    _Float16* lB0 = &Bsh[(w * 32) * 32];                                      \
    _Float16* lB1 = &Bsh[(w * 32 + 16) * 32];                                 \
    int aoff[4], boff[4];                                                     \
    _Pragma("unroll")                                                         \
    for (int i = 0; i < 4; ++i) {                                             \
        const int ra = wr * 64 + i * 16 + lr;                                 \
        const int rb = wc * 64 + i * 16 + lr;                                 \
        aoff[i] = ra * 32 + ((g ^ ((ra >> 1) & 3)) * 8);                      \
        boff[i] = rb * 32 + ((g ^ ((rb >> 1) & 3)) * 8);                      \
    }                                                                         \
    f32x4 acc[4][4] = {};

#define GEMM_LOOP()                                                           \
    for (int k0 = 0; k0 < DIMC; k0 += 32) {                                   \
        gl2lds16(gA0 + k0, lA0);                                              \
        gl2lds16(gA1 + k0, lA1);                                              \
        gl2lds16(gB0 + k0, lB0);                                              \
        gl2lds16(gB1 + k0, lB1);                                              \
        __syncthreads();                                                      \
        f16x8 bhf[4];                                                         \
        _Pragma("unroll")                                                     \
        for (int ni = 0; ni < 4; ++ni)                                        \
            bhf[ni] = *(const f16x8*)&Bsh[boff[ni]];                          \
        _Pragma("unroll")                                                     \
        for (int mi = 0; mi < 4; ++mi) {                                      \
            f16x8 ahf = *(const f16x8*)&Ash[aoff[mi]];                        \
            _Pragma("unroll")                                                 \
            for (int ni = 0; ni < 4; ++ni)                                    \
                acc[mi][ni] = MFMA(ahf, bhf[ni], acc[mi][ni]);                \
        }                                                                     \
        __syncthreads();                                                      \
    }

// ---------------------------------------------------------------------------
// QKV GEMM with fused fp16 output layouts (q/k raw per-head, v transposed).
// ---------------------------------------------------------------------------
__global__ __launch_bounds__(256) void gemm_qkv(
    const _Float16* __restrict__ Ah, const _Float16* __restrict__ Bh,
    const float* __restrict__ bias,
    _Float16* __restrict__ Qh, _Float16* __restrict__ Kh,
    _Float16* __restrict__ Vt)
{
    __shared__ __attribute__((aligned(16))) _Float16 Ash[128 * 32];
    __shared__ __attribute__((aligned(16))) _Float16 Bsh[128 * 32];
    GEMM_PRE()
    GEMM_LOOP()

    const int nb = bn >> 7;          // 0..71
    const int typ = nb / NH;         // 0=q 1=k 2=v
    const int h = nb % NH;

    if (typ == 2) {
#pragma unroll
        for (int mi = 0; mi < 4; ++mi) {
            const int sbase = bm + wr * 64 + mi * 16 + g * 4;
#pragma unroll
            for (int ni = 0; ni < 4; ++ni) {
                const int col = wc * 64 + ni * 16 + lr;
                const float bv = bias[bn + col];
                f16x4 vv;
                vv.x = (_Float16)(acc[mi][ni][0] + bv);
                vv.y = (_Float16)(acc[mi][ni][1] + bv);
                vv.z = (_Float16)(acc[mi][ni][2] + bv);
                vv.w = (_Float16)(acc[mi][ni][3] + bv);
                *(f16x4*)&Vt[((size_t)h * HD + col) * S_TOT + sbase] = vv;
            }
        }
    } else {
        _Float16* dst = (typ ? Kh : Qh) + (size_t)h * S_TOT * HD;
#pragma unroll
        for (int mi = 0; mi < 4; ++mi)
#pragma unroll
            for (int ni = 0; ni < 4; ++ni) {
                const int col = wc * 64 + ni * 16 + lr;
                const float bv = bias[bn + col];
#pragma unroll
                for (int e = 0; e < 4; ++e) {
                    const int r = bm + wr * 64 + mi * 16 + g * 4 + e;
                    dst[(size_t)r * HD + col] = (_Float16)(acc[mi][ni][e] + bv);
                }
            }
    }
}

// ---------------------------------------------------------------------------
// Out-proj GEMM: f32 out with hidden/encoder row remap.
// ---------------------------------------------------------------------------
__global__ __launch_bounds__(256) void gemm_out(
    const _Float16* __restrict__ Ah, const _Float16* __restrict__ Bh,
    const float* __restrict__ bias, float* __restrict__ C)
{
    __shared__ __attribute__((aligned(16))) _Float16 Ash[128 * 32];
    __shared__ __attribute__((aligned(16))) _Float16 Bsh[128 * 32];
    GEMM_PRE()
    GEMM_LOOP()

#pragma unroll
    for (int mi = 0; mi < 4; ++mi)
#pragma unroll
        for (int ni = 0; ni < 4; ++ni) {
            const int cl = bn + wc * 64 + ni * 16 + lr;
            const float bv = bias[cl];
#pragma unroll
            for (int e = 0; e < 4; ++e) {
                const int r = bm + wr * 64 + mi * 16 + g * 4 + e;
                const int gr = (r < S_TXT) ? (S_IMG + r) : (r - S_TXT);
                C[(size_t)gr * DIMC + cl] = acc[mi][ni][e] + bv;
            }
        }
}

// ---------------------------------------------------------------------------
// In-place LayerNorm + RoPE on fp16 Q/K rows [NH][S][128]; Q pre-scaled.
// ---------------------------------------------------------------------------
__global__ __launch_bounds__(256) void ln_rope_inplace(
    _Float16* __restrict__ Qh, _Float16* __restrict__ Kh,
    const float* __restrict__ cost, const float* __restrict__ sint)
{
    const int wave = threadIdx.x >> 6;
    const int lane = threadIdx.x & 63;
    const int task = blockIdx.x * 4 + wave;
    const int s = task / 48;
    const int rem = task % 48;
    const int qk = rem / 24;
    const int h = rem % 24;

    _Float16* p = (qk ? Kh : Qh) + ((size_t)h * S_TOT + s) * HD + lane * 2;
    f16x2 xv = *(const f16x2*)p;
    float x0 = (float)xv.x, x1 = (float)xv.y;

    float sum = x0 + x1;
    float sq = x0 * x0 + x1 * x1;
#pragma unroll
    for (int off = 1; off < 64; off <<= 1) {
        sum += __shfl_xor(sum, off, 64);
        sq  += __shfl_xor(sq, off, 64);
    }
    const float mu = sum * (1.0f / 128.0f);
    const float var = sq * (1.0f / 128.0f) - mu * mu;
    const float rstd = rsqrtf(var + 1e-5f);
    float y0 = (x0 - mu) * rstd;
    float y1 = (x1 - mu) * rstd;

    if (s >= S_TXT) {
        const int ip = s - S_TXT;
        const float c = cost[ip * 64 + lane];
        const float sn = sint[ip * 64 + lane];
        const float o0 = y0 * c - y1 * sn;
        const float o1 = y1 * c + y0 * sn;
        y0 = o0; y1 = o1;
    }
    if (qk == 0) { y0 *= QSCALE; y1 *= QSCALE; }

    f16x2 hv; hv.x = (_Float16)y0; hv.y = (_Float16)y1;
    *(f16x2*)p = hv;
}

// ---------------------------------------------------------------------------
// Flash attention, fp16 MFMA, log2-domain softmax, defer-max (THR=11).
// Block = (128 q, head): 4 waves x 32 q, 256 threads. KVBLK=64.
// Each K/V LDS fragment feeds TWO MFMAs (two Q-sets) -> K/V LDS reads halved
// vs the 8-wave version (attn was LDS-read-bound). XOR-granule swizzles.
// Grid 432 = 8 XCDs x 54; each XCD owns exactly 3 heads.
// ---------------------------------------------------------------------------
__global__ __launch_bounds__(256) void attn_mfma(
    const _Float16* __restrict__ Qg, const _Float16* __restrict__ Kg,
    const _Float16* __restrict__ Vg, _Float16* __restrict__ aoh)
{
    __shared__ __attribute__((aligned(16))) _Float16 Ksh[4 * 64 * 32]; // 16 KB
    __shared__ __attribute__((aligned(16))) _Float16 Vsh[128 * 64];    // 16 KB
    __shared__ __attribute__((aligned(16))) _Float16 Pah[4 * 32 * 64]; // 16 KB

    const int wgid = ((int)blockIdx.x & 7) * 54 + ((int)blockIdx.x >> 3);
    const int h = wgid / 18;
    const int q0 = (wgid % 18) * 128;
    const int tid = threadIdx.x;
    const int w = tid >> 6, l = tid & 63;
    const int lr = l & 15, g = l >> 4;

    // Q fragments: wave owns rows [q0+w*32, q0+w*32+32), two 16-q sets
    const int qrow = q0 + w * 32 + lr;
    const _Float16* qb0 = Qg + ((size_t)h * S_TOT + qrow) * HD + g * 8;
    const _Float16* qb1 = qb0 + (size_t)16 * HD;
    f16x8 qh0[4], qh1[4];
#pragma unroll
    for (int db = 0; db < 4; ++db) {
        qh0[db] = *(const f16x8*)(qb0 + db * 32);
        qh1[db] = *(const f16x8*)(qb1 + db * 32);
    }

    f32x4 o0[8] = {}, o1[8] = {};
    float m0 = -3.0e38f, l0s = 0.0f;
    float m1 = -3.0e38f, l1s = 0.0f;

    // swizzled read offsets
    const int kxr = (lr >> 1) & 3;
    const int px  = lr & 7;
    int ksl[4];
#pragma unroll
    for (int db = 0; db < 4; ++db) ksl[db] = (g ^ kxr ^ db) * 8;
    const int vs0 = (g ^ px) * 8;
    const int vs1 = ((4 + g) ^ px) * 8;

    // staging (256 thr, 64B each for K and V) — R7-verified layout
    const int kkv = tid >> 2, kdb = tid & 3;
    const int kx = (kkv >> 1) & 3;
    const int kbase = kdb * 2048 + kkv * 32;
    const int vd = tid >> 1;
    const int vbase = vd * 64;
    const int vx = vd & 7;
    const int vg0 = (tid & 1) * 4;
    const _Float16* gK = Kg + ((size_t)h * S_TOT + kkv) * HD + kdb * 32;
    const _Float16* gV = Vg + ((size_t)h * HD + vd) * S_TOT + (tid & 1) * 32;

    uint4 rK0, rK1, rK2, rK3, rV0, rV1, rV2, rV3;
#define LOADKV(kv0) { \
    rK0 = *(const uint4*)(gK + (size_t)(kv0) * HD);      rK1 = *(const uint4*)(gK + (size_t)(kv0) * HD + 8); \
    rK2 = *(const uint4*)(gK + (size_t)(kv0) * HD + 16); rK3 = *(const uint4*)(gK + (size_t)(kv0) * HD + 24); \
    rV0 = *(const uint4*)(gV + (kv0));      rV1 = *(const uint4*)(gV + (kv0) + 8); \
    rV2 = *(const uint4*)(gV + (kv0) + 16); rV3 = *(const uint4*)(gV + (kv0) + 24); }

    LOADKV(0);

    for (int kb = 0; kb < S_TOT / 64; ++kb) {
        __syncthreads();
        *(uint4*)&Ksh[kbase + ((0 ^ kx ^ kdb) * 8)] = rK0;
        *(uint4*)&Ksh[kbase + ((1 ^ kx ^ kdb) * 8)] = rK1;
        *(uint4*)&Ksh[kbase + ((2 ^ kx ^ kdb) * 8)] = rK2;
        *(uint4*)&Ksh[kbase + ((3 ^ kx ^ kdb) * 8)] = rK3;
        *(uint4*)&Vsh[vbase + (((vg0 + 0) ^ vx) * 8)] = rV0;
        *(uint4*)&Vsh[vbase + (((vg0 + 1) ^ vx) * 8)] = rV1;
        *(uint4*)&Vsh[vbase + (((vg0 + 2) ^ vx) * 8)] = rV2;
        *(uint4*)&Vsh[vbase + (((vg0 + 3) ^ vx) * 8)] = rV3;
        __syncthreads();
        if (kb + 1 < S_TOT / 64) LOADKV((kb + 1) * 64);

        // scores: 4 frags x 2 q-sets; each K fragment feeds both sets
        f32x4 sT0[4] = {}, sT1[4] = {};
        __builtin_amdgcn_s_setprio(1);
#pragma unroll
        for (int db = 0; db < 4; ++db)
#pragma unroll
            for (int mf = 0; mf < 4; ++mf) {
                f16x8 kf = *(const f16x8*)&Ksh[db * 2048 + (mf * 16 + lr) * 32 + ksl[db]];
                sT0[mf] = MFMA(kf, qh0[db], sT0[mf]);
                sT1[mf] = MFMA(kf, qh1[db], sT1[mf]);
            }
        __builtin_amdgcn_s_setprio(0);

        // per-lane max (set0: q=lr, set1: q=lr+16)
        float pm0 = -3.0e38f, pm1 = -3.0e38f;
#pragma unroll
        for (int mf = 0; mf < 4; ++mf)
#pragma unroll
            for (int e = 0; e < 4; ++e) {
                pm0 = fmaxf(pm0, sT0[mf][e]);
                pm1 = fmaxf(pm1, sT1[mf][e]);
            }
        pm0 = fmaxf(pm0, __shfl_xor(pm0, 16, 64));
        pm0 = fmaxf(pm0, __shfl_xor(pm0, 32, 64));
        pm1 = fmaxf(pm1, __shfl_xor(pm1, 16, 64));
        pm1 = fmaxf(pm1, __shfl_xor(pm1, 32, 64));

        // defer-max (log2 domain, THR=11), both sets rescaled together
        if (__any((pm0 > m0 + 11.0f) || (pm1 > m1 + 11.0f))) {
            const float mn0 = fmaxf(m0, pm0);
            const float al0 = exp2f(m0 - mn0);
            l0s *= al0; m0 = mn0;
            const float mn1 = fmaxf(m1, pm1);
            const float al1 = exp2f(m1 - mn1);
            l1s *= al1; m1 = mn1;
            const float a0 = __shfl(al0, g * 4 + 0, 64);
            const float a1 = __shfl(al0, g * 4 + 1, 64);
            const float a2 = __shfl(al0, g * 4 + 2, 64);
            const float a3 = __shfl(al0, g * 4 + 3, 64);
            const float b0 = __shfl(al1, g * 4 + 0, 64);
            const float b1 = __shfl(al1, g * 4 + 1, 64);
            const float b2 = __shfl(al1, g * 4 + 2, 64);
            const float b3 = __shfl(al1, g * 4 + 3, 64);
#pragma unroll
            for (int df = 0; df < 8; ++df) {
                o0[df][0] *= a0; o0[df][1] *= a1; o0[df][2] *= a2; o0[df][3] *= a3;
                o1[df][0] *= b0; o1[df][1] *= b1; o1[df][2] *= b2; o1[df][3] *= b3;
            }
        }

        float rs0 = 0.0f, rs1 = 0.0f;
        float ex0[4][4], ex1[4][4];
#pragma unroll
        for (int mf = 0; mf < 4; ++mf)
#pragma unroll
            for (int e = 0; e < 4; ++e) {
                const float p0 = exp2f(sT0[mf][e] - m0);
                const float p1 = exp2f(sT1[mf][e] - m1);
                ex0[mf][e] = p0; rs0 += p0;
                ex1[mf][e] = p1; rs1 += p1;
            }
        rs0 += __shfl_xor(rs0, 16, 64);
        rs0 += __shfl_xor(rs0, 32, 64);
        rs1 += __shfl_xor(rs1, 16, 64);
        rs1 += __shfl_xor(rs1, 32, 64);
        l0s += rs0;
        l1s += rs1;

        // publish P: set0 rows lr, set1 rows 16+lr (same px = lr&7)
        {
            const int pb0 = w * 2048 + lr * 64;
            const int pb1 = w * 2048 + (16 + lr) * 64;
#pragma unroll
            for (int mf = 0; mf < 4; ++mf) {
                const int slot = ((mf * 2 + (g >> 1)) ^ px) * 8 + (g & 1) * 4;
                f16x2 t0; t0.x = (_Float16)ex0[mf][0]; t0.y = (_Float16)ex0[mf][1];
                f16x2 t1; t1.x = (_Float16)ex0[mf][2]; t1.y = (_Float16)ex0[mf][3];
                f16x2 u0; u0.x = (_Float16)ex1[mf][0]; u0.y = (_Float16)ex1[mf][1];
                f16x2 u1; u1.x = (_Float16)ex1[mf][2]; u1.y = (_Float16)ex1[mf][3];
                *(f16x2*)&Pah[pb0 + slot]     = t0;
                *(f16x2*)&Pah[pb0 + slot + 2] = t1;
                *(f16x2*)&Pah[pb1 + slot]     = u0;
                *(f16x2*)&Pah[pb1 + slot + 2] = u1;
            }
        }

        // PV: each V fragment feeds both q-sets
        f16x8 pa0a = *(const f16x8*)&Pah[w * 2048 + lr * 64 + vs0];
        f16x8 pa0b = *(const f16x8*)&Pah[w * 2048 + lr * 64 + vs1];
        f16x8 pa1a = *(const f16x8*)&Pah[w * 2048 + (16 + lr) * 64 + vs0];
        f16x8 pa1b = *(const f16x8*)&Pah[w * 2048 + (16 + lr) * 64 + vs1];
        __builtin_amdgcn_s_setprio(1);
#pragma unroll
        for (int df = 0; df < 8; ++df) {
            f16x8 vf0 = *(const f16x8*)&Vsh[(df * 16 + lr) * 64 + vs0];
            f16x8 vf1 = *(const f16x8*)&Vsh[(df * 16 + lr) * 64 + vs1];
            o0[df] = MFMA(pa0a, vf0, o0[df]);
            o0[df] = MFMA(pa0b, vf1, o0[df]);
            o1[df] = MFMA(pa1a, vf0, o1[df]);
            o1[df] = MFMA(pa1b, vf1, o1[df]);
        }
        __builtin_amdgcn_s_setprio(0);
    }
#undef LOADKV

    const float i0 = 1.0f / l0s;
    const float i1 = 1.0f / l1s;
    const float c0 = __shfl(i0, g * 4 + 0, 64);
    const float c1 = __shfl(i0, g * 4 + 1, 64);
    const float c2 = __shfl(i0, g * 4 + 2, 64);
    const float c3 = __shfl(i0, g * 4 + 3, 64);
    const float d0 = __shfl(i1, g * 4 + 0, 64);
    const float d1 = __shfl(i1, g * 4 + 1, 64);
    const float d2 = __shfl(i1, g * 4 + 2, 64);
    const float d3 = __shfl(i1, g * 4 + 3, 64);
    const float cc[4] = {c0, c1, c2, c3};
    const float dd[4] = {d0, d1, d2, d3};
#pragma unroll
    for (int df = 0; df < 8; ++df)
#pragma unroll
        for (int e = 0; e < 4; ++e) {
            const int r0 = q0 + w * 32 + g * 4 + e;
            const int col = h * HD + df * 16 + lr;
            aoh[(size_t)r0 * DIMC + col] = (_Float16)(o0[df][e] * cc[e]);
            aoh[(size_t)(r0 + 16) * DIMC + col] = (_Float16)(o1[df][e] * dd[e]);
        }
}

// ---------------------------------------------------------------------------
extern "C" void kernel_launch(void* const* d_in, const int* in_sizes, int n_in,
                              void* d_out, int out_size, void* d_ws, size_t ws_size,
                              hipStream_t stream)
{
    const float* hid  = (const float*)d_in[0];
    const float* enc  = (const float*)d_in[1];
    const float* cost = (const float*)d_in[2];
    const float* sint = (const float*)d_in[3];
    const float* Wqkv = (const float*)d_in[4];
    const float* bqkv = (const float*)d_in[5];
    const float* Wout = (const float*)d_in[6];
    const float* bout = (const float*)d_in[7];
    float* out = (float*)d_out;

    char* ws = (char*)d_ws;
    _Float16* Qh  = (_Float16*)(ws + 0);          // 14.16 MB [NH][S][128]
    _Float16* Kh  = (_Float16*)(ws + 14155776);   // 14.16 MB
    _Float16* Vth = (_Float16*)(ws + 28311552);   // 14.16 MB [NH][128][S]
    _Float16* aoh = (_Float16*)(ws + 42467328);   // 14.16 MB [S][3072]
    _Float16* xh  = (_Float16*)(ws + 56623104);   // 14.16 MB
    _Float16* Wth = (_Float16*)(ws + 70778880);   // 56.62 MB Wqkv^T fp16
    _Float16* W2h = (_Float16*)(ws + 127401984);  // 18.87 MB Wout^T fp16

    prep<<<S_TOT + 144 * 48 + 48 * 48, 256, 0, stream>>>(
        enc, hid, Wqkv, Wout, xh, Wth, W2h);
    gemm_qkv<<<18 * 72, 256, 0, stream>>>(xh, Wth, bqkv, Qh, Kh, Vth);
    ln_rope_inplace<<<(S_TOT * 48) / 4, 256, 0, stream>>>(Qh, Kh, cost, sint);
    attn_mfma<<<432, 256, 0, stream>>>(Qh, Kh, Vth, aoh);
    gemm_out<<<18 * 24, 256, 0, stream>>>(aoh, W2h, bout, out);
}

// Round 14
// 390.833 us; speedup vs baseline: 1.1490x; 1.1490x over previous
//
#include <hip/hip_runtime.h>

#define DIMC 3072
#define NH 24
#define HD 128
#define QKV_N 9216
#define S_TXT 256
#define S_IMG 2048
#define S_TOT 2304

typedef _Float16 f16x8 __attribute__((ext_vector_type(8)));
typedef _Float16 f16x4 __attribute__((ext_vector_type(4)));
typedef _Float16 f16x2 __attribute__((ext_vector_type(2)));
typedef float f32x4 __attribute__((ext_vector_type(4)));

#define MFMA(A, B, C) __builtin_amdgcn_mfma_f32_16x16x32_f16(A, B, C, 0, 0, 0)

// scale(1/sqrt(128)) * log2(e): scores computed directly in log2 domain
#define QSCALE (0.08838834764831845f * 1.4426950408889634f)

// direct global->LDS async copy, 16B per lane; lds base must be wave-uniform
__device__ __forceinline__ void gl2lds16(const _Float16* g, _Float16* l) {
    __builtin_amdgcn_global_load_lds(
        (const __attribute__((address_space(1))) unsigned int*)g,
        (__attribute__((address_space(3))) unsigned int*)l,
        16, 0, 0);
}

// ---------------------------------------------------------------------------
// prep: one launch for concat->fp16 + both W transposes.
// ---------------------------------------------------------------------------
__global__ __launch_bounds__(256) void prep(
    const float* __restrict__ enc, const float* __restrict__ hid,
    const float* __restrict__ Wqkv, const float* __restrict__ Wout,
    _Float16* __restrict__ xh, _Float16* __restrict__ Wth,
    _Float16* __restrict__ W2h)
{
    __shared__ float T[64][68];
    const int bid = blockIdx.x;
    const int t = threadIdx.x;

    if (bid < S_TOT) {
        const int s = bid;
        const float* src = (s < S_TXT) ? enc + (size_t)s * DIMC
                                       : hid + (size_t)(s - S_TXT) * DIMC;
#pragma unroll
        for (int it = 0; it < 3; ++it) {
            const int i = (it * 256 + t) * 4;
            float4 v = *(const float4*)(src + i);
            f16x4 hv;
            hv.x = (_Float16)v.x; hv.y = (_Float16)v.y;
            hv.z = (_Float16)v.z; hv.w = (_Float16)v.w;
            *(f16x4*)(xh + (size_t)s * DIMC + i) = hv;
        }
        return;
    }

    const float* W;
    _Float16* Th;
    int n0, k0, ldw;
    if (bid < S_TOT + 144 * 48) {
        const int b2 = bid - S_TOT;
        W = Wqkv; Th = Wth; ldw = QKV_N;
        n0 = (b2 % 144) * 64; k0 = (b2 / 144) * 64;
    } else {
        const int b2 = bid - S_TOT - 144 * 48;
        W = Wout; Th = W2h; ldw = DIMC;
        n0 = (b2 % 48) * 64; k0 = (b2 / 48) * 64;
    }
    {
        const int r = t >> 2, c4 = (t & 3) * 16;
#pragma unroll
        for (int j = 0; j < 4; ++j) {
            float4 v = *(const float4*)(W + (size_t)(k0 + r) * ldw + n0 + c4 + j * 4);
            *(float4*)&T[r][c4 + j * 4] = v;
        }
    }
    __syncthreads();
    const int nr = t >> 2, kp = (t & 3) * 16;
    f16x8 hv0, hv1;
#pragma unroll
    for (int j = 0; j < 8; ++j) hv0[j] = (_Float16)T[kp + j][nr];
#pragma unroll
    for (int j = 0; j < 8; ++j) hv1[j] = (_Float16)T[kp + 8 + j][nr];
    _Float16* dh = Th + (size_t)(n0 + nr) * DIMC + k0 + kp;
    *(f16x8*)(dh) = hv0; *(f16x8*)(dh + 8) = hv1;
}

// ===========================================================================
// 2-phase single-buffer GEMM core (R10-verified: 183 us, MfmaUtil 31%,
// 0 conflicts). 128x128 tile, BK=32, 4 waves 2x2, gl2lds w16.
// T1 XCD-chunked swizzle + T2 both-sides slot-XOR.
// ===========================================================================
#define GEMM_PRE()                                                            \
    const int cpx = (int)gridDim.x >> 3;                                      \
    const int wgid = (blockIdx.x & 7) * cpx + (blockIdx.x >> 3);              \
    const int bm = (wgid % 18) * 128;                                         \
    const int bn = (wgid / 18) * 128;                                         \
    const int tid = threadIdx.x;                                              \
    const int l = tid & 63, w = tid >> 6;                                     \
    const int wr = w >> 1, wc = w & 1;                                        \
    const int lr = l & 15, g = l >> 4;                                        \
    const int srow0 = w * 32 + (l >> 2);                                      \
    const int srow1 = srow0 + 16;                                             \
    const int skp0 = (((l & 3) ^ ((srow0 >> 1) & 3)) * 8);                    \
    const int skp1 = (((l & 3) ^ ((srow1 >> 1) & 3)) * 8);                    \
    const _Float16* gA0 = Ah + (size_t)(bm + srow0) * DIMC + skp0;            \
    const _Float16* gA1 = Ah + (size_t)(bm + srow1) * DIMC + skp1;            \
    const _Float16* gB0 = Bh + (size_t)(bn + srow0) * DIMC + skp0;            \
    const _Float16* gB1 = Bh + (size_t)(bn + srow1) * DIMC + skp1;            \
    _Float16* lA0 = &Ash[(w * 32) * 32];                                      \
    _Float16* lA1 = &Ash[(w * 32 + 16) * 32];                                 \
    _Float16* lB0 = &Bsh[(w * 32) * 32];                                      \
    _Float16* lB1 = &Bsh[(w * 32 + 16) * 32];                                 \
    int aoff[4], boff[4];                                                     \
    _Pragma("unroll")                                                         \
    for (int i = 0; i < 4; ++i) {                                             \
        const int ra = wr * 64 + i * 16 + lr;                                 \
        const int rb = wc * 64 + i * 16 + lr;                                 \
        aoff[i] = ra * 32 + ((g ^ ((ra >> 1) & 3)) * 8);                      \
        boff[i] = rb * 32 + ((g ^ ((rb >> 1) & 3)) * 8);                      \
    }                                                                         \
    f32x4 acc[4][4] = {};

#define GEMM_LOOP()                                                           \
    for (int k0 = 0; k0 < DIMC; k0 += 32) {                                   \
        gl2lds16(gA0 + k0, lA0);                                              \
        gl2lds16(gA1 + k0, lA1);                                              \
        gl2lds16(gB0 + k0, lB0);                                              \
        gl2lds16(gB1 + k0, lB1);                                              \
        __syncthreads();                                                      \
        f16x8 bhf[4];                                                         \
        _Pragma("unroll")                                                     \
        for (int ni = 0; ni < 4; ++ni)                                        \
            bhf[ni] = *(const f16x8*)&Bsh[boff[ni]];                          \
        _Pragma("unroll")                                                     \
        for (int mi = 0; mi < 4; ++mi) {                                      \
            f16x8 ahf = *(const f16x8*)&Ash[aoff[mi]];                        \
            _Pragma("unroll")                                                 \
            for (int ni = 0; ni < 4; ++ni)                                    \
                acc[mi][ni] = MFMA(ahf, bhf[ni], acc[mi][ni]);                \
        }                                                                     \
        __syncthreads();                                                      \
    }

// ---------------------------------------------------------------------------
// QKV GEMM with fused fp16 output layouts (q/k raw per-head, v transposed).
// ---------------------------------------------------------------------------
__global__ __launch_bounds__(256) void gemm_qkv(
    const _Float16* __restrict__ Ah, const _Float16* __restrict__ Bh,
    const float* __restrict__ bias,
    _Float16* __restrict__ Qh, _Float16* __restrict__ Kh,
    _Float16* __restrict__ Vt)
{
    __shared__ __attribute__((aligned(16))) _Float16 Ash[128 * 32];
    __shared__ __attribute__((aligned(16))) _Float16 Bsh[128 * 32];
    GEMM_PRE()
    GEMM_LOOP()

    const int nb = bn >> 7;          // 0..71
    const int typ = nb / NH;         // 0=q 1=k 2=v
    const int h = nb % NH;

    if (typ == 2) {
#pragma unroll
        for (int mi = 0; mi < 4; ++mi) {
            const int sbase = bm + wr * 64 + mi * 16 + g * 4;
#pragma unroll
            for (int ni = 0; ni < 4; ++ni) {
                const int col = wc * 64 + ni * 16 + lr;
                const float bv = bias[bn + col];
                f16x4 vv;
                vv.x = (_Float16)(acc[mi][ni][0] + bv);
                vv.y = (_Float16)(acc[mi][ni][1] + bv);
                vv.z = (_Float16)(acc[mi][ni][2] + bv);
                vv.w = (_Float16)(acc[mi][ni][3] + bv);
                *(f16x4*)&Vt[((size_t)h * HD + col) * S_TOT + sbase] = vv;
            }
        }
    } else {
        _Float16* dst = (typ ? Kh : Qh) + (size_t)h * S_TOT * HD;
#pragma unroll
        for (int mi = 0; mi < 4; ++mi)
#pragma unroll
            for (int ni = 0; ni < 4; ++ni) {
                const int col = wc * 64 + ni * 16 + lr;
                const float bv = bias[bn + col];
#pragma unroll
                for (int e = 0; e < 4; ++e) {
                    const int r = bm + wr * 64 + mi * 16 + g * 4 + e;
                    dst[(size_t)r * HD + col] = (_Float16)(acc[mi][ni][e] + bv);
                }
            }
    }
}

// ---------------------------------------------------------------------------
// Out-proj GEMM: f32 out with hidden/encoder row remap.
// ---------------------------------------------------------------------------
__global__ __launch_bounds__(256) void gemm_out(
    const _Float16* __restrict__ Ah, const _Float16* __restrict__ Bh,
    const float* __restrict__ bias, float* __restrict__ C)
{
    __shared__ __attribute__((aligned(16))) _Float16 Ash[128 * 32];
    __shared__ __attribute__((aligned(16))) _Float16 Bsh[128 * 32];
    GEMM_PRE()
    GEMM_LOOP()

#pragma unroll
    for (int mi = 0; mi < 4; ++mi)
#pragma unroll
        for (int ni = 0; ni < 4; ++ni) {
            const int cl = bn + wc * 64 + ni * 16 + lr;
            const float bv = bias[cl];
#pragma unroll
            for (int e = 0; e < 4; ++e) {
                const int r = bm + wr * 64 + mi * 16 + g * 4 + e;
                const int gr = (r < S_TXT) ? (S_IMG + r) : (r - S_TXT);
                C[(size_t)gr * DIMC + cl] = acc[mi][ni][e] + bv;
            }
        }
}

// ---------------------------------------------------------------------------
// In-place LayerNorm + RoPE on fp16 Q/K rows [NH][S][128]; Q pre-scaled.
// ---------------------------------------------------------------------------
__global__ __launch_bounds__(256) void ln_rope_inplace(
    _Float16* __restrict__ Qh, _Float16* __restrict__ Kh,
    const float* __restrict__ cost, const float* __restrict__ sint)
{
    const int wave = threadIdx.x >> 6;
    const int lane = threadIdx.x & 63;
    const int task = blockIdx.x * 4 + wave;
    const int s = task / 48;
    const int rem = task % 48;
    const int qk = rem / 24;
    const int h = rem % 24;

    _Float16* p = (qk ? Kh : Qh) + ((size_t)h * S_TOT + s) * HD + lane * 2;
    f16x2 xv = *(const f16x2*)p;
    float x0 = (float)xv.x, x1 = (float)xv.y;

    float sum = x0 + x1;
    float sq = x0 * x0 + x1 * x1;
#pragma unroll
    for (int off = 1; off < 64; off <<= 1) {
        sum += __shfl_xor(sum, off, 64);
        sq  += __shfl_xor(sq, off, 64);
    }
    const float mu = sum * (1.0f / 128.0f);
    const float var = sq * (1.0f / 128.0f) - mu * mu;
    const float rstd = rsqrtf(var + 1e-5f);
    float y0 = (x0 - mu) * rstd;
    float y1 = (x1 - mu) * rstd;

    if (s >= S_TXT) {
        const int ip = s - S_TXT;
        const float c = cost[ip * 64 + lane];
        const float sn = sint[ip * 64 + lane];
        const float o0 = y0 * c - y1 * sn;
        const float o1 = y1 * c + y0 * sn;
        y0 = o0; y1 = o1;
    }
    if (qk == 0) { y0 *= QSCALE; y1 *= QSCALE; }

    f16x2 hv; hv.x = (_Float16)y0; hv.y = (_Float16)y1;
    *(f16x2*)p = hv;
}

// ---------------------------------------------------------------------------
// Flash attention, fp16 MFMA, log2-domain softmax, defer-max (THR=11).
// Block = (128 q, head), 8 waves x 16 q, 512 threads. KVBLK=64.
// Swapped scores K@Q^T. XOR-granule-swizzled LDS, 48KB.
// Grid 432 = 8 XCDs x 54; each XCD owns exactly 3 heads.  (R10-verified)
// ---------------------------------------------------------------------------
__global__ __launch_bounds__(512) void attn_mfma(
    const _Float16* __restrict__ Qg, const _Float16* __restrict__ Kg,
    const _Float16* __restrict__ Vg, _Float16* __restrict__ aoh)
{
    __shared__ __attribute__((aligned(16))) _Float16 Ksh[4 * 64 * 32]; // 16 KB
    __shared__ __attribute__((aligned(16))) _Float16 Vsh[128 * 64];    // 16 KB
    __shared__ __attribute__((aligned(16))) _Float16 Pah[8 * 16 * 64]; // 16 KB

    const int wgid = ((int)blockIdx.x & 7) * 54 + ((int)blockIdx.x >> 3);
    const int h = wgid / 18;
    const int q0 = (wgid % 18) * 128;
    const int tid = threadIdx.x;
    const int w = tid >> 6, l = tid & 63;
    const int lr = l & 15, g = l >> 4;

    const int qrow = q0 + w * 16 + lr;
    const _Float16* qb = Qg + ((size_t)h * S_TOT + qrow) * HD + g * 8;
    f16x8 qh[4];
#pragma unroll
    for (int db = 0; db < 4; ++db)
        qh[db] = *(const f16x8*)(qb + db * 32);

    f32x4 o[8] = {};
    float mrow = -3.0e38f, lrow = 0.0f;

    const int kxr = (lr >> 1) & 3;
    const int px  = lr & 7;
    int ksl[4];
#pragma unroll
    for (int db = 0; db < 4; ++db) ksl[db] = (g ^ kxr ^ db) * 8;
    const int vs0 = (g ^ px) * 8;
    const int vs1 = ((4 + g) ^ px) * 8;

    const int kkv = tid >> 3, kd = tid & 7;
    const int kdb = kd >> 1, kg0 = (kd & 1) * 2;
    const int kx = (kkv >> 1) & 3;
    const int kbase = kdb * 2048 + kkv * 32;
    const int vd = tid >> 2, vh = tid & 3;
    const int vx = vd & 7;
    const int vbase = vd * 64;
    const int vg0 = vh * 2;
    const _Float16* gK = Kg + ((size_t)h * S_TOT + kkv) * HD + kd * 16;
    const _Float16* gV = Vg + ((size_t)h * HD + vd) * S_TOT + vh * 16;

    uint4 rK0, rK1, rV0, rV1;
#define LOADKV(kv0) { \
    rK0 = *(const uint4*)(gK + (size_t)(kv0) * HD);     rK1 = *(const uint4*)(gK + (size_t)(kv0) * HD + 8); \
    rV0 = *(const uint4*)(gV + (kv0));                  rV1 = *(const uint4*)(gV + (kv0) + 8); }

    LOADKV(0);

    for (int kb = 0; kb < S_TOT / 64; ++kb) {
        __syncthreads();
        *(uint4*)&Ksh[kbase + (((kg0 + 0) ^ kx ^ kdb) * 8)] = rK0;
        *(uint4*)&Ksh[kbase + (((kg0 + 1) ^ kx ^ kdb) * 8)] = rK1;
        *(uint4*)&Vsh[vbase + (((vg0 + 0) ^ vx) * 8)] = rV0;
        *(uint4*)&Vsh[vbase + (((vg0 + 1) ^ vx) * 8)] = rV1;
        __syncthreads();
        if (kb + 1 < S_TOT / 64) LOADKV((kb + 1) * 64);

        f32x4 sT[4] = {};
        __builtin_amdgcn_s_setprio(1);
#pragma unroll
        for (int db = 0; db < 4; ++db)
#pragma unroll
            for (int mf = 0; mf < 4; ++mf) {
                f16x8 kf = *(const f16x8*)&Ksh[db * 2048 + (mf * 16 + lr) * 32 + ksl[db]];
                sT[mf] = MFMA(kf, qh[db], sT[mf]);
            }
        __builtin_amdgcn_s_setprio(0);

        float pm = -3.0e38f;
#pragma unroll
        for (int mf = 0; mf < 4; ++mf)
#pragma unroll
            for (int e = 0; e < 4; ++e)
                pm = fmaxf(pm, sT[mf][e]);
        pm = fmaxf(pm, __shfl_xor(pm, 16, 64));
        pm = fmaxf(pm, __shfl_xor(pm, 32, 64));

        if (__any(pm > mrow + 11.0f)) {
            const float mnew = fmaxf(mrow, pm);
            const float alpha = exp2f(mrow - mnew);
            lrow *= alpha;
            mrow = mnew;
            const float a0 = __shfl(alpha, g * 4 + 0, 64);
            const float a1 = __shfl(alpha, g * 4 + 1, 64);
            const float a2 = __shfl(alpha, g * 4 + 2, 64);
            const float a3 = __shfl(alpha, g * 4 + 3, 64);
#pragma unroll
            for (int df = 0; df < 8; ++df) {
                o[df][0] *= a0; o[df][1] *= a1; o[df][2] *= a2; o[df][3] *= a3;
            }
        }

        float rs = 0.0f;
        float ex_[4][4];
#pragma unroll
        for (int mf = 0; mf < 4; ++mf)
#pragma unroll
            for (int e = 0; e < 4; ++e) {
                const float pv = exp2f(sT[mf][e] - mrow);
                ex_[mf][e] = pv;
                rs += pv;
            }
        rs += __shfl_xor(rs, 16, 64);
        rs += __shfl_xor(rs, 32, 64);
        lrow += rs;

        {
            const int pbase = w * 1024 + lr * 64;
#pragma unroll
            for (int mf = 0; mf < 4; ++mf) {
                const int slot = ((mf * 2 + (g >> 1)) ^ px) * 8 + (g & 1) * 4;
                f16x2 t0; t0.x = (_Float16)ex_[mf][0]; t0.y = (_Float16)ex_[mf][1];
                f16x2 t1; t1.x = (_Float16)ex_[mf][2]; t1.y = (_Float16)ex_[mf][3];
                *(f16x2*)&Pah[pbase + slot]     = t0;
                *(f16x2*)&Pah[pbase + slot + 2] = t1;
            }
        }

        f16x8 pa0 = *(const f16x8*)&Pah[w * 1024 + lr * 64 + vs0];
        f16x8 pa1 = *(const f16x8*)&Pah[w * 1024 + lr * 64 + vs1];
        __builtin_amdgcn_s_setprio(1);
#pragma unroll
        for (int df = 0; df < 8; ++df) {
            f16x8 vf0 = *(const f16x8*)&Vsh[(df * 16 + lr) * 64 + vs0];
            f16x8 vf1 = *(const f16x8*)&Vsh[(df * 16 + lr) * 64 + vs1];
            o[df] = MFMA(pa0, vf0, o[df]);
            o[df] = MFMA(pa1, vf1, o[df]);
        }
        __builtin_amdgcn_s_setprio(0);
    }
#undef LOADKV

    const float inv = 1.0f / lrow;
    const float b0 = __shfl(inv, g * 4 + 0, 64);
    const float b1 = __shfl(inv, g * 4 + 1, 64);
    const float b2 = __shfl(inv, g * 4 + 2, 64);
    const float b3 = __shfl(inv, g * 4 + 3, 64);
    const float bb[4] = {b0, b1, b2, b3};
#pragma unroll
    for (int df = 0; df < 8; ++df)
#pragma unroll
        for (int e = 0; e < 4; ++e) {
            const int r = q0 + w * 16 + g * 4 + e;
            aoh[(size_t)r * DIMC + h * HD + df * 16 + lr] = (_Float16)(o[df][e] * bb[e]);
        }
}

// ---------------------------------------------------------------------------
extern "C" void kernel_launch(void* const* d_in, const int* in_sizes, int n_in,
                              void* d_out, int out_size, void* d_ws, size_t ws_size,
                              hipStream_t stream)
{
    const float* hid  = (const float*)d_in[0];
    const float* enc  = (const float*)d_in[1];
    const float* cost = (const float*)d_in[2];
    const float* sint = (const float*)d_in[3];
    const float* Wqkv = (const float*)d_in[4];
    const float* bqkv = (const float*)d_in[5];
    const float* Wout = (const float*)d_in[6];
    const float* bout = (const float*)d_in[7];
    float* out = (float*)d_out;

    char* ws = (char*)d_ws;
    _Float16* Qh  = (_Float16*)(ws + 0);          // 14.16 MB [NH][S][128]
    _Float16* Kh  = (_Float16*)(ws + 14155776);   // 14.16 MB
    _Float16* Vth = (_Float16*)(ws + 28311552);   // 14.16 MB [NH][128][S]
    _Float16* aoh = (_Float16*)(ws + 42467328);   // 14.16 MB [S][3072]
    _Float16* xh  = (_Float16*)(ws + 56623104);   // 14.16 MB
    _Float16* Wth = (_Float16*)(ws + 70778880);   // 56.62 MB Wqkv^T fp16
    _Float16* W2h = (_Float16*)(ws + 127401984);  // 18.87 MB Wout^T fp16

    prep<<<S_TOT + 144 * 48 + 48 * 48, 256, 0, stream>>>(
        enc, hid, Wqkv, Wout, xh, Wth, W2h);
    gemm_qkv<<<18 * 72, 256, 0, stream>>>(xh, Wth, bqkv, Qh, Kh, Vth);
    ln_rope_inplace<<<(S_TOT * 48) / 4, 256, 0, stream>>>(Qh, Kh, cost, sint);
    attn_mfma<<<432, 512, 0, stream>>>(Qh, Kh, Vth, aoh);
    gemm_out<<<18 * 24, 256, 0, stream>>>(aoh, W2h, bout, out);
}

// Round 15
// 385.776 us; speedup vs baseline: 1.1641x; 1.0131x over previous
//
#include <hip/hip_runtime.h>

#define DIMC 3072
#define NH 24
#define HD 128
#define QKV_N 9216
#define S_TXT 256
#define S_IMG 2048
#define S_TOT 2304

typedef _Float16 f16x8 __attribute__((ext_vector_type(8)));
typedef _Float16 f16x4 __attribute__((ext_vector_type(4)));
typedef _Float16 f16x2 __attribute__((ext_vector_type(2)));
typedef float f32x4 __attribute__((ext_vector_type(4)));

#define MFMA(A, B, C) __builtin_amdgcn_mfma_f32_16x16x32_f16(A, B, C, 0, 0, 0)

// scale(1/sqrt(128)) * log2(e): scores computed directly in log2 domain
#define QSCALE (0.08838834764831845f * 1.4426950408889634f)

// direct global->LDS async copy, 16B per lane; lds base must be wave-uniform
__device__ __forceinline__ void gl2lds16(const _Float16* g, _Float16* l) {
    __builtin_amdgcn_global_load_lds(
        (const __attribute__((address_space(1))) unsigned int*)g,
        (__attribute__((address_space(3))) unsigned int*)l,
        16, 0, 0);
}

// ---------------------------------------------------------------------------
// prep: one launch for concat->fp16 + both W transposes.
// ---------------------------------------------------------------------------
__global__ __launch_bounds__(256) void prep(
    const float* __restrict__ enc, const float* __restrict__ hid,
    const float* __restrict__ Wqkv, const float* __restrict__ Wout,
    _Float16* __restrict__ xh, _Float16* __restrict__ Wth,
    _Float16* __restrict__ W2h)
{
    __shared__ float T[64][68];
    const int bid = blockIdx.x;
    const int t = threadIdx.x;

    if (bid < S_TOT) {
        const int s = bid;
        const float* src = (s < S_TXT) ? enc + (size_t)s * DIMC
                                       : hid + (size_t)(s - S_TXT) * DIMC;
#pragma unroll
        for (int it = 0; it < 3; ++it) {
            const int i = (it * 256 + t) * 4;
            float4 v = *(const float4*)(src + i);
            f16x4 hv;
            hv.x = (_Float16)v.x; hv.y = (_Float16)v.y;
            hv.z = (_Float16)v.z; hv.w = (_Float16)v.w;
            *(f16x4*)(xh + (size_t)s * DIMC + i) = hv;
        }
        return;
    }

    const float* W;
    _Float16* Th;
    int n0, k0, ldw;
    if (bid < S_TOT + 144 * 48) {
        const int b2 = bid - S_TOT;
        W = Wqkv; Th = Wth; ldw = QKV_N;
        n0 = (b2 % 144) * 64; k0 = (b2 / 144) * 64;
    } else {
        const int b2 = bid - S_TOT - 144 * 48;
        W = Wout; Th = W2h; ldw = DIMC;
        n0 = (b2 % 48) * 64; k0 = (b2 / 48) * 64;
    }
    {
        const int r = t >> 2, c4 = (t & 3) * 16;
#pragma unroll
        for (int j = 0; j < 4; ++j) {
            float4 v = *(const float4*)(W + (size_t)(k0 + r) * ldw + n0 + c4 + j * 4);
            *(float4*)&T[r][c4 + j * 4] = v;
        }
    }
    __syncthreads();
    const int nr = t >> 2, kp = (t & 3) * 16;
    f16x8 hv0, hv1;
#pragma unroll
    for (int j = 0; j < 8; ++j) hv0[j] = (_Float16)T[kp + j][nr];
#pragma unroll
    for (int j = 0; j < 8; ++j) hv1[j] = (_Float16)T[kp + 8 + j][nr];
    _Float16* dh = Th + (size_t)(n0 + nr) * DIMC + k0 + kp;
    *(f16x8*)(dh) = hv0; *(f16x8*)(dh + 8) = hv1;
}

// ===========================================================================
// 2-phase single-buffer GEMM core, BK=64 (R10 structure, barrier cost
// amortized 2x). 128x128 tile, 4 waves 2x2, gl2lds w16, LDS 32 KB.
// T1 XCD-chunked swizzle; T2 both-sides 8-slot XOR: physical slot p of row
// holds logical k-slot p ^ (row&7); read slot (kk*4+g) ^ (row&7).
// ===========================================================================
#define GEMM_PRE()                                                            \
    const int cpx = (int)gridDim.x >> 3;                                      \
    const int wgid = (blockIdx.x & 7) * cpx + (blockIdx.x >> 3);              \
    const int bm = (wgid % 18) * 128;                                         \
    const int bn = (wgid / 18) * 128;                                         \
    const int tid = threadIdx.x;                                              \
    const int l = tid & 63, w = tid >> 6;                                     \
    const int wr = w >> 1, wc = w & 1;                                        \
    const int lr = l & 15, g = l >> 4;                                        \
    const int srow = w * 32 + (l >> 3);                                       \
    const int skp = (((l & 7) ^ (l >> 3)) * 8);                               \
    const _Float16* gA0 = Ah + (size_t)(bm + srow) * DIMC + skp;              \
    const _Float16* gA1 = Ah + (size_t)(bm + srow + 8) * DIMC + skp;          \
    const _Float16* gA2 = Ah + (size_t)(bm + srow + 16) * DIMC + skp;         \
    const _Float16* gA3 = Ah + (size_t)(bm + srow + 24) * DIMC + skp;         \
    const _Float16* gB0 = Bh + (size_t)(bn + srow) * DIMC + skp;              \
    const _Float16* gB1 = Bh + (size_t)(bn + srow + 8) * DIMC + skp;          \
    const _Float16* gB2 = Bh + (size_t)(bn + srow + 16) * DIMC + skp;         \
    const _Float16* gB3 = Bh + (size_t)(bn + srow + 24) * DIMC + skp;         \
    _Float16* lA0 = &Ash[(w * 32) * 64];                                      \
    _Float16* lA1 = &Ash[(w * 32 + 8) * 64];                                  \
    _Float16* lA2 = &Ash[(w * 32 + 16) * 64];                                 \
    _Float16* lA3 = &Ash[(w * 32 + 24) * 64];                                 \
    _Float16* lB0 = &Bsh[(w * 32) * 64];                                      \
    _Float16* lB1 = &Bsh[(w * 32 + 8) * 64];                                  \
    _Float16* lB2 = &Bsh[(w * 32 + 16) * 64];                                 \
    _Float16* lB3 = &Bsh[(w * 32 + 24) * 64];                                 \
    int aoff0[4], aoff1[4], boff0[4], boff1[4];                               \
    _Pragma("unroll")                                                         \
    for (int i = 0; i < 4; ++i) {                                             \
        const int ra = wr * 64 + i * 16 + lr;                                 \
        const int rb = wc * 64 + i * 16 + lr;                                 \
        aoff0[i] = ra * 64 + ((g ^ (lr & 7)) * 8);                            \
        aoff1[i] = ra * 64 + (((4 + g) ^ (lr & 7)) * 8);                      \
        boff0[i] = rb * 64 + ((g ^ (lr & 7)) * 8);                            \
        boff1[i] = rb * 64 + (((4 + g) ^ (lr & 7)) * 8);                      \
    }                                                                         \
    f32x4 acc[4][4] = {};

#define GEMM_LOOP()                                                           \
    for (int k0 = 0; k0 < DIMC; k0 += 64) {                                   \
        gl2lds16(gA0 + k0, lA0);                                              \
        gl2lds16(gA1 + k0, lA1);                                              \
        gl2lds16(gA2 + k0, lA2);                                              \
        gl2lds16(gA3 + k0, lA3);                                              \
        gl2lds16(gB0 + k0, lB0);                                              \
        gl2lds16(gB1 + k0, lB1);                                              \
        gl2lds16(gB2 + k0, lB2);                                              \
        gl2lds16(gB3 + k0, lB3);                                              \
        __syncthreads();                                                      \
        {                                                                     \
            f16x8 bhf[4];                                                     \
            _Pragma("unroll")                                                 \
            for (int ni = 0; ni < 4; ++ni)                                    \
                bhf[ni] = *(const f16x8*)&Bsh[boff0[ni]];                     \
            _Pragma("unroll")                                                 \
            for (int mi = 0; mi < 4; ++mi) {                                  \
                f16x8 ahf = *(const f16x8*)&Ash[aoff0[mi]];                   \
                _Pragma("unroll")                                             \
                for (int ni = 0; ni < 4; ++ni)                                \
                    acc[mi][ni] = MFMA(ahf, bhf[ni], acc[mi][ni]);            \
            }                                                                 \
        }                                                                     \
        {                                                                     \
            f16x8 bhf[4];                                                     \
            _Pragma("unroll")                                                 \
            for (int ni = 0; ni < 4; ++ni)                                    \
                bhf[ni] = *(const f16x8*)&Bsh[boff1[ni]];                     \
            _Pragma("unroll")                                                 \
            for (int mi = 0; mi < 4; ++mi) {                                  \
                f16x8 ahf = *(const f16x8*)&Ash[aoff1[mi]];                   \
                _Pragma("unroll")                                             \
                for (int ni = 0; ni < 4; ++ni)                                \
                    acc[mi][ni] = MFMA(ahf, bhf[ni], acc[mi][ni]);            \
            }                                                                 \
        }                                                                     \
        __syncthreads();                                                      \
    }

// ---------------------------------------------------------------------------
// QKV GEMM with fused fp16 output layouts (q/k raw per-head, v transposed).
// ---------------------------------------------------------------------------
__global__ __launch_bounds__(256) void gemm_qkv(
    const _Float16* __restrict__ Ah, const _Float16* __restrict__ Bh,
    const float* __restrict__ bias,
    _Float16* __restrict__ Qh, _Float16* __restrict__ Kh,
    _Float16* __restrict__ Vt)
{
    __shared__ __attribute__((aligned(16))) _Float16 Ash[128 * 64];
    __shared__ __attribute__((aligned(16))) _Float16 Bsh[128 * 64];
    GEMM_PRE()
    GEMM_LOOP()

    const int nb = bn >> 7;          // 0..71
    const int typ = nb / NH;         // 0=q 1=k 2=v
    const int h = nb % NH;

    if (typ == 2) {
#pragma unroll
        for (int mi = 0; mi < 4; ++mi) {
            const int sbase = bm + wr * 64 + mi * 16 + g * 4;
#pragma unroll
            for (int ni = 0; ni < 4; ++ni) {
                const int col = wc * 64 + ni * 16 + lr;
                const float bv = bias[bn + col];
                f16x4 vv;
                vv.x = (_Float16)(acc[mi][ni][0] + bv);
                vv.y = (_Float16)(acc[mi][ni][1] + bv);
                vv.z = (_Float16)(acc[mi][ni][2] + bv);
                vv.w = (_Float16)(acc[mi][ni][3] + bv);
                *(f16x4*)&Vt[((size_t)h * HD + col) * S_TOT + sbase] = vv;
            }
        }
    } else {
        _Float16* dst = (typ ? Kh : Qh) + (size_t)h * S_TOT * HD;
#pragma unroll
        for (int mi = 0; mi < 4; ++mi)
#pragma unroll
            for (int ni = 0; ni < 4; ++ni) {
                const int col = wc * 64 + ni * 16 + lr;
                const float bv = bias[bn + col];
#pragma unroll
                for (int e = 0; e < 4; ++e) {
                    const int r = bm + wr * 64 + mi * 16 + g * 4 + e;
                    dst[(size_t)r * HD + col] = (_Float16)(acc[mi][ni][e] + bv);
                }
            }
    }
}

// ---------------------------------------------------------------------------
// Out-proj GEMM: f32 out with hidden/encoder row remap.
// ---------------------------------------------------------------------------
__global__ __launch_bounds__(256) void gemm_out(
    const _Float16* __restrict__ Ah, const _Float16* __restrict__ Bh,
    const float* __restrict__ bias, float* __restrict__ C)
{
    __shared__ __attribute__((aligned(16))) _Float16 Ash[128 * 64];
    __shared__ __attribute__((aligned(16))) _Float16 Bsh[128 * 64];
    GEMM_PRE()
    GEMM_LOOP()

#pragma unroll
    for (int mi = 0; mi < 4; ++mi)
#pragma unroll
        for (int ni = 0; ni < 4; ++ni) {
            const int cl = bn + wc * 64 + ni * 16 + lr;
            const float bv = bias[cl];
#pragma unroll
            for (int e = 0; e < 4; ++e) {
                const int r = bm + wr * 64 + mi * 16 + g * 4 + e;
                const int gr = (r < S_TXT) ? (S_IMG + r) : (r - S_TXT);
                C[(size_t)gr * DIMC + cl] = acc[mi][ni][e] + bv;
            }
        }
}

// ---------------------------------------------------------------------------
// In-place LayerNorm + RoPE on fp16 Q/K rows [NH][S][128]; Q pre-scaled.
// ---------------------------------------------------------------------------
__global__ __launch_bounds__(256) void ln_rope_inplace(
    _Float16* __restrict__ Qh, _Float16* __restrict__ Kh,
    const float* __restrict__ cost, const float* __restrict__ sint)
{
    const int wave = threadIdx.x >> 6;
    const int lane = threadIdx.x & 63;
    const int task = blockIdx.x * 4 + wave;
    const int s = task / 48;
    const int rem = task % 48;
    const int qk = rem / 24;
    const int h = rem % 24;

    _Float16* p = (qk ? Kh : Qh) + ((size_t)h * S_TOT + s) * HD + lane * 2;
    f16x2 xv = *(const f16x2*)p;
    float x0 = (float)xv.x, x1 = (float)xv.y;

    float sum = x0 + x1;
    float sq = x0 * x0 + x1 * x1;
#pragma unroll
    for (int off = 1; off < 64; off <<= 1) {
        sum += __shfl_xor(sum, off, 64);
        sq  += __shfl_xor(sq, off, 64);
    }
    const float mu = sum * (1.0f / 128.0f);
    const float var = sq * (1.0f / 128.0f) - mu * mu;
    const float rstd = rsqrtf(var + 1e-5f);
    float y0 = (x0 - mu) * rstd;
    float y1 = (x1 - mu) * rstd;

    if (s >= S_TXT) {
        const int ip = s - S_TXT;
        const float c = cost[ip * 64 + lane];
        const float sn = sint[ip * 64 + lane];
        const float o0 = y0 * c - y1 * sn;
        const float o1 = y1 * c + y0 * sn;
        y0 = o0; y1 = o1;
    }
    if (qk == 0) { y0 *= QSCALE; y1 *= QSCALE; }

    f16x2 hv; hv.x = (_Float16)y0; hv.y = (_Float16)y1;
    *(f16x2*)p = hv;
}

// ---------------------------------------------------------------------------
// Flash attention, fp16 MFMA, log2-domain softmax, defer-max (THR=11).
// Block = (128 q, head), 8 waves x 16 q, 512 threads. KVBLK=64.
// Swapped scores K@Q^T. XOR-granule-swizzled LDS, 48KB.
// Grid 432 = 8 XCDs x 54; each XCD owns exactly 3 heads.  (R10-verified)
// ---------------------------------------------------------------------------
__global__ __launch_bounds__(512) void attn_mfma(
    const _Float16* __restrict__ Qg, const _Float16* __restrict__ Kg,
    const _Float16* __restrict__ Vg, _Float16* __restrict__ aoh)
{
    __shared__ __attribute__((aligned(16))) _Float16 Ksh[4 * 64 * 32]; // 16 KB
    __shared__ __attribute__((aligned(16))) _Float16 Vsh[128 * 64];    // 16 KB
    __shared__ __attribute__((aligned(16))) _Float16 Pah[8 * 16 * 64]; // 16 KB

    const int wgid = ((int)blockIdx.x & 7) * 54 + ((int)blockIdx.x >> 3);
    const int h = wgid / 18;
    const int q0 = (wgid % 18) * 128;
    const int tid = threadIdx.x;
    const int w = tid >> 6, l = tid & 63;
    const int lr = l & 15, g = l >> 4;

    const int qrow = q0 + w * 16 + lr;
    const _Float16* qb = Qg + ((size_t)h * S_TOT + qrow) * HD + g * 8;
    f16x8 qh[4];
#pragma unroll
    for (int db = 0; db < 4; ++db)
        qh[db] = *(const f16x8*)(qb + db * 32);

    f32x4 o[8] = {};
    float mrow = -3.0e38f, lrow = 0.0f;

    const int kxr = (lr >> 1) & 3;
    const int px  = lr & 7;
    int ksl[4];
#pragma unroll
    for (int db = 0; db < 4; ++db) ksl[db] = (g ^ kxr ^ db) * 8;
    const int vs0 = (g ^ px) * 8;
    const int vs1 = ((4 + g) ^ px) * 8;

    const int kkv = tid >> 3, kd = tid & 7;
    const int kdb = kd >> 1, kg0 = (kd & 1) * 2;
    const int kx = (kkv >> 1) & 3;
    const int kbase = kdb * 2048 + kkv * 32;
    const int vd = tid >> 2, vh = tid & 3;
    const int vx = vd & 7;
    const int vbase = vd * 64;
    const int vg0 = vh * 2;
    const _Float16* gK = Kg + ((size_t)h * S_TOT + kkv) * HD + kd * 16;
    const _Float16* gV = Vg + ((size_t)h * HD + vd) * S_TOT + vh * 16;

    uint4 rK0, rK1, rV0, rV1;
#define LOADKV(kv0) { \
    rK0 = *(const uint4*)(gK + (size_t)(kv0) * HD);     rK1 = *(const uint4*)(gK + (size_t)(kv0) * HD + 8); \
    rV0 = *(const uint4*)(gV + (kv0));                  rV1 = *(const uint4*)(gV + (kv0) + 8); }

    LOADKV(0);

    for (int kb = 0; kb < S_TOT / 64; ++kb) {
        __syncthreads();
        *(uint4*)&Ksh[kbase + (((kg0 + 0) ^ kx ^ kdb) * 8)] = rK0;
        *(uint4*)&Ksh[kbase + (((kg0 + 1) ^ kx ^ kdb) * 8)] = rK1;
        *(uint4*)&Vsh[vbase + (((vg0 + 0) ^ vx) * 8)] = rV0;
        *(uint4*)&Vsh[vbase + (((vg0 + 1) ^ vx) * 8)] = rV1;
        __syncthreads();
        if (kb + 1 < S_TOT / 64) LOADKV((kb + 1) * 64);

        f32x4 sT[4] = {};
        __builtin_amdgcn_s_setprio(1);
#pragma unroll
        for (int db = 0; db < 4; ++db)
#pragma unroll
            for (int mf = 0; mf < 4; ++mf) {
                f16x8 kf = *(const f16x8*)&Ksh[db * 2048 + (mf * 16 + lr) * 32 + ksl[db]];
                sT[mf] = MFMA(kf, qh[db], sT[mf]);
            }
        __builtin_amdgcn_s_setprio(0);

        float pm = -3.0e38f;
#pragma unroll
        for (int mf = 0; mf < 4; ++mf)
#pragma unroll
            for (int e = 0; e < 4; ++e)
                pm = fmaxf(pm, sT[mf][e]);
        pm = fmaxf(pm, __shfl_xor(pm, 16, 64));
        pm = fmaxf(pm, __shfl_xor(pm, 32, 64));

        if (__any(pm > mrow + 11.0f)) {
            const float mnew = fmaxf(mrow, pm);
            const float alpha = exp2f(mrow - mnew);
            lrow *= alpha;
            mrow = mnew;
            const float a0 = __shfl(alpha, g * 4 + 0, 64);
            const float a1 = __shfl(alpha, g * 4 + 1, 64);
            const float a2 = __shfl(alpha, g * 4 + 2, 64);
            const float a3 = __shfl(alpha, g * 4 + 3, 64);
#pragma unroll
            for (int df = 0; df < 8; ++df) {
                o[df][0] *= a0; o[df][1] *= a1; o[df][2] *= a2; o[df][3] *= a3;
            }
        }

        float rs = 0.0f;
        float ex_[4][4];
#pragma unroll
        for (int mf = 0; mf < 4; ++mf)
#pragma unroll
            for (int e = 0; e < 4; ++e) {
                const float pv = exp2f(sT[mf][e] - mrow);
                ex_[mf][e] = pv;
                rs += pv;
            }
        rs += __shfl_xor(rs, 16, 64);
        rs += __shfl_xor(rs, 32, 64);
        lrow += rs;

        {
            const int pbase = w * 1024 + lr * 64;
#pragma unroll
            for (int mf = 0; mf < 4; ++mf) {
                const int slot = ((mf * 2 + (g >> 1)) ^ px) * 8 + (g & 1) * 4;
                f16x2 t0; t0.x = (_Float16)ex_[mf][0]; t0.y = (_Float16)ex_[mf][1];
                f16x2 t1; t1.x = (_Float16)ex_[mf][2]; t1.y = (_Float16)ex_[mf][3];
                *(f16x2*)&Pah[pbase + slot]     = t0;
                *(f16x2*)&Pah[pbase + slot + 2] = t1;
            }
        }

        f16x8 pa0 = *(const f16x8*)&Pah[w * 1024 + lr * 64 + vs0];
        f16x8 pa1 = *(const f16x8*)&Pah[w * 1024 + lr * 64 + vs1];
        __builtin_amdgcn_s_setprio(1);
#pragma unroll
        for (int df = 0; df < 8; ++df) {
            f16x8 vf0 = *(const f16x8*)&Vsh[(df * 16 + lr) * 64 + vs0];
            f16x8 vf1 = *(const f16x8*)&Vsh[(df * 16 + lr) * 64 + vs1];
            o[df] = MFMA(pa0, vf0, o[df]);
            o[df] = MFMA(pa1, vf1, o[df]);
        }
        __builtin_amdgcn_s_setprio(0);
    }
#undef LOADKV

    const float inv = 1.0f / lrow;
    const float b0 = __shfl(inv, g * 4 + 0, 64);
    const float b1 = __shfl(inv, g * 4 + 1, 64);
    const float b2 = __shfl(inv, g * 4 + 2, 64);
    const float b3 = __shfl(inv, g * 4 + 3, 64);
    const float bb[4] = {b0, b1, b2, b3};
#pragma unroll
    for (int df = 0; df < 8; ++df)
#pragma unroll
        for (int e = 0; e < 4; ++e) {
            const int r = q0 + w * 16 + g * 4 + e;
            aoh[(size_t)r * DIMC + h * HD + df * 16 + lr] = (_Float16)(o[df][e] * bb[e]);
        }
}

// ---------------------------------------------------------------------------
extern "C" void kernel_launch(void* const* d_in, const int* in_sizes, int n_in,
                              void* d_out, int out_size, void* d_ws, size_t ws_size,
                              hipStream_t stream)
{
    const float* hid  = (const float*)d_in[0];
    const float* enc  = (const float*)d_in[1];
    const float* cost = (const float*)d_in[2];
    const float* sint = (const float*)d_in[3];
    const float* Wqkv = (const float*)d_in[4];
    const float* bqkv = (const float*)d_in[5];
    const float* Wout = (const float*)d_in[6];
    const float* bout = (const float*)d_in[7];
    float* out = (float*)d_out;

    char* ws = (char*)d_ws;
    _Float16* Qh  = (_Float16*)(ws + 0);          // 14.16 MB [NH][S][128]
    _Float16* Kh  = (_Float16*)(ws + 14155776);   // 14.16 MB
    _Float16* Vth = (_Float16*)(ws + 28311552);   // 14.16 MB [NH][128][S]
    _Float16* aoh = (_Float16*)(ws + 42467328);   // 14.16 MB [S][3072]
    _Float16* xh  = (_Float16*)(ws + 56623104);   // 14.16 MB
    _Float16* Wth = (_Float16*)(ws + 70778880);   // 56.62 MB Wqkv^T fp16
    _Float16* W2h = (_Float16*)(ws + 127401984);  // 18.87 MB Wout^T fp16

    prep<<<S_TOT + 144 * 48 + 48 * 48, 256, 0, stream>>>(
        enc, hid, Wqkv, Wout, xh, Wth, W2h);
    gemm_qkv<<<18 * 72, 256, 0, stream>>>(xh, Wth, bqkv, Qh, Kh, Vth);
    ln_rope_inplace<<<(S_TOT * 48) / 4, 256, 0, stream>>>(Qh, Kh, cost, sint);
    attn_mfma<<<432, 512, 0, stream>>>(Qh, Kh, Vth, aoh);
    gemm_out<<<18 * 24, 256, 0, stream>>>(aoh, W2h, bout, out);
}